// Round 10
// baseline (357.648 us; speedup 1.0000x reference)
//
#include <hip/hip_runtime.h>
#include <hip/hip_bf16.h>
#include <hip/hip_cooperative_groups.h>
#include <stdint.h>

namespace cg = cooperative_groups;

#define NROWS 8192
#define DDIM  768       // elements per row
#define BM 128
#define BN 128
#define BKB 128         // K-bytes per staged tile
#define NKT  (DDIM / BKB)   // 6 K-iterations
#define QSCALE 508.0f   // int8 quant scale: 127/0.25
#define NTGT (2 * NROWS)
#define NPART 128       // partial slots per target
#define NBLK_MAX 768    // cap: 3 blocks/CU * 256 CUs

typedef int v4i  __attribute__((ext_vector_type(4)));
typedef int v16i __attribute__((ext_vector_type(16)));

__device__ __forceinline__ int imax(int a, int b) { return a > b ? a : b; }

__device__ __forceinline__ v16i vmax16(v16i a, v16i b) {
    v16i r;
    #pragma unroll
    for (int i = 0; i < 16; ++i) r[i] = imax(a[i], b[i]);
    return r;
}

__device__ __forceinline__ void async_ld16(const void* g, uintptr_t lds_addr) {
    __builtin_amdgcn_global_load_lds(
        (const __attribute__((address_space(1))) void*)(uintptr_t)g,
        (__attribute__((address_space(3))) void*)(uint32_t)lds_addr,
        16, 0, 0);
}

__device__ __forceinline__ int pack4(float4 v, float k) {
    int x0 = __float2int_rn(v.x * k); x0 = imax(-127, x0); x0 = x0 > 127 ? 127 : x0;
    int x1 = __float2int_rn(v.y * k); x1 = imax(-127, x1); x1 = x1 > 127 ? 127 : x1;
    int x2 = __float2int_rn(v.z * k); x2 = imax(-127, x2); x2 = x2 > 127 ? 127 : x2;
    int x3 = __float2int_rn(v.w * k); x3 = imax(-127, x3); x3 = x3 > 127 ? 127 : x3;
    return (x0 & 0xff) | ((x1 & 0xff) << 8) | ((x2 & 0xff) << 16) | ((x3 & 0xff) << 24);
}

// ================= fused cooperative persistent kernel =================
// R10: round-9 failed at LAUNCH (output stayed zero, no hang) — almost
// certainly grid 768 > runtime's co-residency cap. Grid is now supplied by
// an occupancy query and the kernel is grid-size-agnostic everywhere.
__global__ __launch_bounds__(256, 3) void mega_kernel(
        const float* __restrict__ ex, const float* __restrict__ ey,
        char* __restrict__ Xq, char* __restrict__ Yqf,
        int* __restrict__ P, int* __restrict__ ctrs,
        float* __restrict__ bsums, float* __restrict__ out) {
    __shared__ __align__(16) char S[18432];   // A staging / epilogue / reduction scratch
    __shared__ int tile_k;

    cg::grid_group grid = cg::this_grid();

    const int tid  = threadIdx.x;
    const int lane = tid & 63;
    const int wave = tid >> 6;
    const int blk  = blockIdx.x;
    const int nwave = gridDim.x * 4;

    // ---- phase 0+1: init tile counters; row-normalize + int8 quantize ----
    if (blk == 0 && tid < 8) atomicExch(&ctrs[tid], 0);   // ws is 0xAA-poisoned

    for (int row = blk * 4 + wave; row < NTGT; row += nwave) {
        const float* src = (row < NROWS) ? ex + (size_t)row * DDIM
                                         : ey + (size_t)(row - NROWS) * DDIM;
        const float4* s4 = (const float4*)src;
        float4 a = s4[lane], b = s4[lane + 64], c = s4[lane + 128];
        float ss = a.x*a.x + a.y*a.y + a.z*a.z + a.w*a.w
                 + b.x*b.x + b.y*b.y + b.z*b.z + b.w*b.w
                 + c.x*c.x + c.y*c.y + c.z*c.z + c.w*c.w;
        #pragma unroll
        for (int off = 32; off > 0; off >>= 1) ss += __shfl_xor(ss, off, 64);
        float k = rsqrtf(ss) * QSCALE;    // norms ~27.7; 1e-8 clamp never binds
        if (row < NROWS) {                // X -> row-major
            int* d4 = (int*)(Xq + (size_t)row * DDIM);
            d4[lane]       = pack4(a, k);
            d4[lane + 64]  = pack4(b, k);
            d4[lane + 128] = pack4(c, k);
        } else {                          // Y -> fragment-major
            int r  = row - NROWS;
            int cb = r >> 5, fr_ = r & 31;
            int cbase = lane >> 2, wofs = lane & 3;
            int* dq = (int*)Yqf;
            dq[((cb * 48 + cbase     ) * 32 + fr_) * 4 + wofs] = pack4(a, k);
            dq[((cb * 48 + cbase + 16) * 32 + fr_) * 4 + wofs] = pack4(b, k);
            dq[((cb * 48 + cbase + 32) * 32 + fr_) * 4 + wofs] = pack4(c, k);
        }
    }

    grid.sync();

    // ---- phase 2: int8 NT-GEMM tiles, dynamic per-XCD-class queue ----
    const int wm = wave >> 1;
    const int wn = wave & 1;
    const int fr = lane & 31;
    const int h  = lane >> 5;
    const int aRow = (wm * 64 + fr) * BKB;
    const int fswz = fr & 7;
    const int srow = lane >> 3;
    const int sswz = (lane & 7) ^ srow;
    const uintptr_t ldsA = (uintptr_t)(void*)S + (unsigned)(wave * 4096);
    const int g = blk & 7;   // XCD class; tile b = g + 8k keeps round-6 L2 locality

    for (;;) {
        __syncthreads();                       // LDS reuse fence + uniform tile fetch
        if (tid == 0) tile_k = atomicAdd(&ctrs[g], 1);
        __syncthreads();
        const int k = tile_k;
        if (k >= 512) break;                   // 4096 tiles / 8 classes
        const int p_ = g + 8 * (k >> 8);
        const int w  = k & 255;
        const int bx = (p_ & 3) * 16 + (w & 15);
        const int by = (p_ >> 2) * 16 + (w >> 4);
        const int row0 = by * BM;
        const int col0 = bx * BN;

        const char* gA = Xq + (size_t)(row0 + wave * 32 + srow) * DDIM + sswz * 16;
        const int cb0 = (col0 >> 5) + wn * 2;
        const v4i* gB = (const v4i*)Yqf + ((size_t)(cb0 * 48 + h) * 32 + fr);

        v16i acc[2][2] = {};

        for (int kt = 0; kt < NKT; ++kt) {
            const char* ga = gA + kt * BKB;
            #pragma unroll
            for (int j = 0; j < 4; ++j)
                async_ld16(ga + j * (8 * DDIM), ldsA + j * 1024);
            v4i bf[4][2];
            #pragma unroll
            for (int ks = 0; ks < 4; ++ks)
                #pragma unroll
                for (int nt = 0; nt < 2; ++nt)
                    bf[ks][nt] = gB[(nt * 48 + kt * 8 + ks * 2) * 32];
            __syncthreads();                   // drains A staging + B loads
            #pragma unroll
            for (int ks = 0; ks < 4; ++ks) {
                v4i af[2];
                const int swz = ((ks * 2 + h) ^ fswz) * 16;
                #pragma unroll
                for (int mt = 0; mt < 2; ++mt)
                    af[mt] = *(const v4i*)(S + aRow + mt * (32 * BKB) + swz);
                #pragma unroll
                for (int mt = 0; mt < 2; ++mt)
                    #pragma unroll
                    for (int nt = 0; nt < 2; ++nt)
                        acc[mt][nt] = __builtin_amdgcn_mfma_i32_32x32x32_i8(
                            af[mt], bf[ks][nt], acc[mt][nt], 0, 0, 0);
            }
            __syncthreads();                   // staging readers done before next stage
        }

        // C/D (32x32): col = lane&31 (=fr), row = (reg&3) + 8*(reg>>2) + 4*h
        v16i m[2] = { vmax16(acc[0][0], acc[0][1]), vmax16(acc[1][0], acc[1][1]) };

        #pragma unroll
        for (int nt = 0; nt < 2; ++nt) {       // col partials (cheap direction)
            v16i c = vmax16(acc[0][nt], acc[1][nt]);
            int v = c[0];
            #pragma unroll
            for (int i = 1; i < 16; ++i) v = imax(v, c[i]);
            v = imax(v, __shfl_xor(v, 32, 64));
            if (h == 0) {
                int col = col0 + wn * 64 + nt * 32 + fr;
                P[(size_t)(NROWS + col) * NPART + by * 2 + wm] = v;   // sole writer
            }
        }

        int* T = (int*)(void*)S + wave * 1152; // row partials via LDS transpose
        const int rrow = lane & 31, seg = lane >> 5;
        #pragma unroll
        for (int mt = 0; mt < 2; ++mt) {
            #pragma unroll
            for (int reg = 0; reg < 16; ++reg) {
                int rl = (reg & 3) + 8 * (reg >> 2) + 4 * h;
                T[rl * 36 + fr] = m[mt][reg];
            }
            __builtin_amdgcn_s_waitcnt(0);
            const v4i* tr = (const v4i*)(T + rrow * 36 + seg * 16);
            v4i a0 = tr[0], a1 = tr[1], a2 = tr[2], a3 = tr[3];
            v4i m01 = { imax(a0[0],a1[0]), imax(a0[1],a1[1]), imax(a0[2],a1[2]), imax(a0[3],a1[3]) };
            v4i m23 = { imax(a2[0],a3[0]), imax(a2[1],a3[1]), imax(a2[2],a3[2]), imax(a2[3],a3[3]) };
            int v = imax(imax(m01[0], m23[0]), imax(m01[1], m23[1]));
            v = imax(v, imax(imax(m01[2], m23[2]), imax(m01[3], m23[3])));
            v = imax(v, __shfl_xor(v, 32, 64));
            if (seg == 0) {
                int row = row0 + wm * 64 + mt * 32 + rrow;
                P[(size_t)row * NPART + bx * 2 + wn] = v;             // sole writer
            }
            __builtin_amdgcn_s_waitcnt(0);
        }
    }

    __threadfence();
    grid.sync();

    // ---- phase 3: per-target max -> entropy partial sums ----
    const float dq = 1.0f / (QSCALE * QSCALE);
    float s_row = 0.0f, s_col = 0.0f;
    for (int t = blk * 4 + wave; t < NTGT; t += nwave) {
        const int* p = P + (size_t)t * NPART;
        int v = imax(p[lane], p[lane + 64]);
        #pragma unroll
        for (int off = 1; off < 64; off <<= 1)
            v = imax(v, __shfl_xor(v, off, 64));
        if (lane == 0) {
            float f = (float)v * dq;
            float z = f * (1.0f / 0.3f);
            float c = -0.5f * z * z + 0.28503427f;
            float e = expf(c) * c;
            if (t < NROWS) s_row += e; else s_col += e;
        }
    }
    __syncthreads();                           // S free for reduction scratch
    float* R = (float*)(void*)S;
    if (lane == 0) { R[wave * 2] = s_row; R[wave * 2 + 1] = s_col; }
    __syncthreads();
    if (tid == 0) {
        bsums[blk * 2]     = R[0] + R[2] + R[4] + R[6];
        bsums[blk * 2 + 1] = R[1] + R[3] + R[5] + R[7];
    }

    __threadfence();
    grid.sync();

    // ---- phase 4: block 0 sums grid partials, writes out ----
    if (blk == 0) {
        float sr = 0.0f, sc = 0.0f;
        for (int i = tid; i < (int)gridDim.x; i += 256) {
            sr += bsums[i * 2];
            sc += bsums[i * 2 + 1];
        }
        #pragma unroll
        for (int off = 32; off > 0; off >>= 1) {
            sr += __shfl_xor(sr, off, 64);
            sc += __shfl_xor(sc, off, 64);
        }
        __syncthreads();
        if (lane == 0) { R[wave * 2] = sr; R[wave * 2 + 1] = sc; }
        __syncthreads();
        if (tid == 0) {
            out[0] = -(R[0] + R[2] + R[4] + R[6]);
            out[1] = -(R[1] + R[3] + R[5] + R[7]);
        }
    }
}

// ================= fallback chain (round-8, proven 155 us) =================
__global__ __launch_bounds__(256) void norm_quant_kernel(
        const float* __restrict__ ex, const float* __restrict__ ey,
        char* __restrict__ Xq, char* __restrict__ Yqf) {
    int row  = blockIdx.x * 4 + (threadIdx.x >> 6);
    int lane = threadIdx.x & 63;
    const float* src = (row < NROWS) ? ex + (size_t)row * DDIM
                                     : ey + (size_t)(row - NROWS) * DDIM;
    const float4* s4 = (const float4*)src;
    float4 a = s4[lane], b = s4[lane + 64], c = s4[lane + 128];
    float ss = a.x*a.x + a.y*a.y + a.z*a.z + a.w*a.w
             + b.x*b.x + b.y*b.y + b.z*b.z + b.w*b.w
             + c.x*c.x + c.y*c.y + c.z*c.z + c.w*c.w;
    #pragma unroll
    for (int off = 32; off > 0; off >>= 1) ss += __shfl_xor(ss, off, 64);
    float k = rsqrtf(ss) * QSCALE;
    if (row < NROWS) {
        int* d4 = (int*)(Xq + (size_t)row * DDIM);
        d4[lane]       = pack4(a, k);
        d4[lane + 64]  = pack4(b, k);
        d4[lane + 128] = pack4(c, k);
    } else {
        int r  = row - NROWS;
        int cb = r >> 5, fr = r & 31;
        int cbase = lane >> 2, wofs = lane & 3;
        int* dq = (int*)Yqf;
        dq[((cb * 48 + cbase     ) * 32 + fr) * 4 + wofs] = pack4(a, k);
        dq[((cb * 48 + cbase + 16) * 32 + fr) * 4 + wofs] = pack4(b, k);
        dq[((cb * 48 + cbase + 32) * 32 + fr) * 4 + wofs] = pack4(c, k);
    }
}

__global__ __launch_bounds__(256, 3) void gemm_max_kernel(
        const char* __restrict__ Xq, const char* __restrict__ Yqf,
        int* __restrict__ P) {
    __shared__ __align__(16) char S[18432];
    const int tid  = threadIdx.x;
    const int lane = tid & 63;
    const int wave = tid >> 6;
    const int wm   = wave >> 1;
    const int wn   = wave & 1;
    const int b    = blockIdx.x;
    const int p_   = (b & 7) + 8 * ((b >> 3) >> 8);
    const int w    = (b >> 3) & 255;
    const int bx   = (p_ & 3) * 16 + (w & 15);
    const int by   = (p_ >> 2) * 16 + (w >> 4);
    const int row0 = by * BM;
    const int col0 = bx * BN;
    const int srow = lane >> 3;
    const int sswz = (lane & 7) ^ srow;
    const char* gA = Xq + (size_t)(row0 + wave * 32 + srow) * DDIM + sswz * 16;
    const uintptr_t ldsA = (uintptr_t)(void*)S + (unsigned)(wave * 4096);
    const int fr = lane & 31;
    const int h  = lane >> 5;
    const int aRow = (wm * 64 + fr) * BKB;
    const int fswz = fr & 7;
    const int cb0 = (col0 >> 5) + wn * 2;
    const v4i* gB = (const v4i*)Yqf + ((size_t)(cb0 * 48 + h) * 32 + fr);

    v16i acc[2][2] = {};
    for (int kt = 0; kt < NKT; ++kt) {
        const char* ga = gA + kt * BKB;
        #pragma unroll
        for (int j = 0; j < 4; ++j)
            async_ld16(ga + j * (8 * DDIM), ldsA + j * 1024);
        v4i bf[4][2];
        #pragma unroll
        for (int ks = 0; ks < 4; ++ks)
            #pragma unroll
            for (int nt = 0; nt < 2; ++nt)
                bf[ks][nt] = gB[(nt * 48 + kt * 8 + ks * 2) * 32];
        __syncthreads();
        #pragma unroll
        for (int ks = 0; ks < 4; ++ks) {
            v4i af[2];
            const int swz = ((ks * 2 + h) ^ fswz) * 16;
            #pragma unroll
            for (int mt = 0; mt < 2; ++mt)
                af[mt] = *(const v4i*)(S + aRow + mt * (32 * BKB) + swz);
            #pragma unroll
            for (int mt = 0; mt < 2; ++mt)
                #pragma unroll
                for (int nt = 0; nt < 2; ++nt)
                    acc[mt][nt] = __builtin_amdgcn_mfma_i32_32x32x32_i8(
                        af[mt], bf[ks][nt], acc[mt][nt], 0, 0, 0);
        }
        __syncthreads();
    }
    v16i m[2] = { vmax16(acc[0][0], acc[0][1]), vmax16(acc[1][0], acc[1][1]) };
    #pragma unroll
    for (int nt = 0; nt < 2; ++nt) {
        v16i c = vmax16(acc[0][nt], acc[1][nt]);
        int v = c[0];
        #pragma unroll
        for (int i = 1; i < 16; ++i) v = imax(v, c[i]);
        v = imax(v, __shfl_xor(v, 32, 64));
        if (h == 0) {
            int col = col0 + wn * 64 + nt * 32 + fr;
            P[(size_t)(NROWS + col) * NPART + by * 2 + wm] = v;
        }
    }
    int* T = (int*)(void*)S + wave * 1152;
    const int rrow = lane & 31, seg = lane >> 5;
    #pragma unroll
    for (int mt = 0; mt < 2; ++mt) {
        #pragma unroll
        for (int reg = 0; reg < 16; ++reg) {
            int rl = (reg & 3) + 8 * (reg >> 2) + 4 * h;
            T[rl * 36 + fr] = m[mt][reg];
        }
        __builtin_amdgcn_s_waitcnt(0);
        const v4i* tr = (const v4i*)(T + rrow * 36 + seg * 16);
        v4i a0 = tr[0], a1 = tr[1], a2 = tr[2], a3 = tr[3];
        v4i m01 = { imax(a0[0],a1[0]), imax(a0[1],a1[1]), imax(a0[2],a1[2]), imax(a0[3],a1[3]) };
        v4i m23 = { imax(a2[0],a3[0]), imax(a2[1],a3[1]), imax(a2[2],a3[2]), imax(a2[3],a3[3]) };
        int v = imax(imax(m01[0], m23[0]), imax(m01[1], m23[1]));
        v = imax(v, imax(imax(m01[2], m23[2]), imax(m01[3], m23[3])));
        v = imax(v, __shfl_xor(v, 32, 64));
        if (seg == 0) {
            int row = row0 + wm * 64 + mt * 32 + rrow;
            P[(size_t)row * NPART + bx * 2 + wn] = v;
        }
        __builtin_amdgcn_s_waitcnt(0);
    }
}

__global__ __launch_bounds__(256) void reduce_kernel(
        const int* __restrict__ P, int* __restrict__ maxes) {
    int t    = blockIdx.x * 4 + (threadIdx.x >> 6);
    int lane = threadIdx.x & 63;
    const int* p = P + (size_t)t * NPART;
    int v = imax(p[lane], p[lane + 64]);
    #pragma unroll
    for (int off = 1; off < 64; off <<= 1)
        v = imax(v, __shfl_xor(v, off, 64));
    if (lane == 0) maxes[t] = v;
}

__global__ __launch_bounds__(256) void finalize_kernel(
        const int* __restrict__ maxes, float* __restrict__ out) {
    int which = blockIdx.x;
    const int* m = maxes + which * NROWS;
    int t = threadIdx.x;
    float s = 0.0f;
    const float dq = 1.0f / (QSCALE * QSCALE);
    for (int i = t; i < NROWS; i += 256) {
        float f = (float)m[i] * dq;
        float z = f * (1.0f / 0.3f);
        float c = -0.5f * z * z + 0.28503427f;
        s += expf(c) * c;
    }
    #pragma unroll
    for (int off = 32; off > 0; off >>= 1) s += __shfl_down(s, off, 64);
    __shared__ float red[4];
    if ((t & 63) == 0) red[t >> 6] = s;
    __syncthreads();
    if (t == 0) out[which] = -(red[0] + red[1] + red[2] + red[3]);
}

extern "C" void kernel_launch(void* const* d_in, const int* in_sizes, int n_in,
                              void* d_out, int out_size, void* d_ws, size_t ws_size,
                              hipStream_t stream) {
    const float* ex = (const float*)d_in[0];
    const float* ey = (const float*)d_in[1];
    float* out = (float*)d_out;

    char* ws   = (char*)d_ws;
    char* Xq   = ws;                                             // 6.29 MB row-major
    char* Yqf  = ws + (size_t)NROWS * DDIM;                      // 6.29 MB fragment-major
    int*  P    = (int*)(ws + (size_t)2 * NROWS * DDIM);          // 8 MB
    int*  maxes = P + (size_t)NTGT * NPART;                      // 64 KB (fallback)
    int*  ctrs = maxes + NTGT;                                   // 8 ints
    float* bsums = (float*)(ctrs + 8);                           // <=768 float2

    // Deterministic host-side decision (query, not a failed launch):
    int maxPerCU = 0;
    hipError_t qerr = hipOccupancyMaxActiveBlocksPerMultiprocessor(
        &maxPerCU, mega_kernel, 256, 0);
    int nblk = (qerr == hipSuccess) ? maxPerCU * 256 : 0;
    if (nblk > NBLK_MAX) nblk = NBLK_MAX;

    if (nblk >= 256) {   // cooperative path: at least 1 block/CU resident
        void* args[] = { (void*)&ex, (void*)&ey, (void*)&Xq, (void*)&Yqf,
                         (void*)&P, (void*)&ctrs, (void*)&bsums, (void*)&out };
        hipLaunchCooperativeKernel((void*)mega_kernel, dim3(nblk), dim3(256),
                                   args, 0, stream);
    } else {             // proven round-8 chain
        hipLaunchKernelGGL(norm_quant_kernel, dim3(2 * NROWS / 4), dim3(256), 0, stream,
                           ex, ey, Xq, Yqf);
        hipLaunchKernelGGL(gemm_max_kernel, dim3((NROWS / BN) * (NROWS / BM)), dim3(256), 0, stream,
                           Xq, Yqf, P);
        hipLaunchKernelGGL(reduce_kernel, dim3(NTGT / 4), dim3(256), 0, stream, P, maxes);
        hipLaunchKernelGGL(finalize_kernel, dim3(2), dim3(256), 0, stream, maxes, out);
    }
}

// Round 11
// 168.963 us; speedup vs baseline: 2.1167x; 2.1167x over previous
//
#include <hip/hip_runtime.h>
#include <hip/hip_bf16.h>
#include <stdint.h>

#define NROWS 8192
#define DDIM  768       // elements per row
#define QSCALE 508.0f   // int8 quant scale: 127/0.25
#define NPROW 128       // row partial slots (64 bx * 2 wn)
#define NPCOL 64        // col partial slots (32 by * 2 wm)

typedef int v4i  __attribute__((ext_vector_type(4)));
typedef int v16i __attribute__((ext_vector_type(16)));

__device__ __forceinline__ int imax(int a, int b) { return a > b ? a : b; }

__device__ __forceinline__ v16i vmax16(v16i a, v16i b) {
    v16i r;
    #pragma unroll
    for (int i = 0; i < 16; ++i) r[i] = imax(a[i], b[i]);
    return r;
}

__device__ __forceinline__ int pack4(float4 v, float k) {
    int x0 = __float2int_rn(v.x * k); x0 = imax(-127, x0); x0 = x0 > 127 ? 127 : x0;
    int x1 = __float2int_rn(v.y * k); x1 = imax(-127, x1); x1 = x1 > 127 ? 127 : x1;
    int x2 = __float2int_rn(v.z * k); x2 = imax(-127, x2); x2 = x2 > 127 ? 127 : x2;
    int x3 = __float2int_rn(v.w * k); x3 = imax(-127, x3); x3 = x3 > 127 ? 127 : x3;
    return (x0 & 0xff) | ((x1 & 0xff) << 8) | ((x2 & 0xff) << 16) | ((x3 & 0xff) << 24);
}

// ---- 1: row-normalize + int8 quantize, BOTH outputs fragment-major ----
// k-chunk c (16B) of row (rb*32+fr) lives at Q[((rb*48+c)*32+fr)*16].
// Also zeroes the entropy accumulators + done counter (ws is 0xAA-poisoned).
__global__ __launch_bounds__(256) void norm_quant_kernel(
        const float* __restrict__ ex, const float* __restrict__ ey,
        char* __restrict__ Xqf, char* __restrict__ Yqf,
        float* __restrict__ accum, int* __restrict__ done) {
    if (blockIdx.x == 0 && threadIdx.x == 0) {
        accum[0] = 0.0f; accum[1] = 0.0f; *done = 0;
    }
    int row  = blockIdx.x * 4 + (threadIdx.x >> 6);
    int lane = threadIdx.x & 63;
    const float* src; int* dq;
    int rr;
    if (row < NROWS) { src = ex + (size_t)row * DDIM;           dq = (int*)Xqf; rr = row; }
    else             { rr = row - NROWS; src = ey + (size_t)rr * DDIM; dq = (int*)Yqf; }
    const float4* s4 = (const float4*)src;
    float4 a = s4[lane], b = s4[lane + 64], c = s4[lane + 128];
    float ss = a.x*a.x + a.y*a.y + a.z*a.z + a.w*a.w
             + b.x*b.x + b.y*b.y + b.z*b.z + b.w*b.w
             + c.x*c.x + c.y*c.y + c.z*c.z + c.w*c.w;
    #pragma unroll
    for (int off = 32; off > 0; off >>= 1) ss += __shfl_xor(ss, off, 64);
    float k = rsqrtf(ss) * QSCALE;   // norms ~27.7; reference's 1e-8 clamp never binds
    int rb = rr >> 5, fr = rr & 31;
    int cbase = lane >> 2, wofs = lane & 3;    // lane's float4 j covers chunk cbase+j*16
    dq[((rb * 48 + cbase     ) * 32 + fr) * 4 + wofs] = pack4(a, k);
    dq[((rb * 48 + cbase + 16) * 32 + fr) * 4 + wofs] = pack4(b, k);
    dq[((rb * 48 + cbase + 32) * 32 + fr) * 4 + wofs] = pack4(c, k);
}

// ---- 2: BARRIER-FREE int8 NT-GEMM, both operands fragment-major from L2 ----
// Block 256x128, grid 2048; 4 waves in 2x2, wave tile 128x64 = 4x2 of 32x32.
// No LDS, no __syncthreads in the main loop: every fragment is a coalesced
// 16B/lane global load; waves are fully decoupled so the R6-R8 barrier-drain
// stall (MfmaUtil pinned ~33%) disappears. 0.75 KB L2 reads per MFMA.
// XCD patch swizzle: class g works a 16x16-block patch for L2 locality.
__global__ __launch_bounds__(256, 2) void gemm_max_kernel(
        const char* __restrict__ Xqf, const char* __restrict__ Yqf,
        int* __restrict__ Prow, int* __restrict__ Pcol) {
    __shared__ __align__(16) char S[18432];   // epilogue transpose scratch only

    const int tid  = threadIdx.x;
    const int lane = tid & 63;
    const int wave = tid >> 6;
    const int wm   = wave >> 1;
    const int wn   = wave & 1;

    const int b  = blockIdx.x;            // 2048 = 8 XCD classes * 256
    const int g  = b & 7, kk = b >> 3;
    const int bx = (g & 3) * 16 + (kk & 15);   // 0..63  (cols / 128)
    const int by = (g >> 2) * 16 + (kk >> 4);  // 0..31  (rows / 256)
    const int row0 = by * 256;
    const int col0 = bx * 128;

    const int fr = lane & 31;             // operand row within 32-block
    const int h  = lane >> 5;             // k-half (16B)

    const v4i* Ab = (const v4i*)Xqf;      // indices in 16B units
    const v4i* Bb = (const v4i*)Yqf;
    int aIdx[4], bIdx[2];
    #pragma unroll
    for (int mt = 0; mt < 4; ++mt)
        aIdx[mt] = ((by * 8 + wm * 4 + mt) * 48 + h) * 32 + fr;
    #pragma unroll
    for (int nt = 0; nt < 2; ++nt)
        bIdx[nt] = ((bx * 4 + wn * 2 + nt) * 48 + h) * 32 + fr;

    v16i acc[4][2] = {};

    #pragma unroll
    for (int kt = 0; kt < 6; ++kt) {
        v4i af[4][4], bf[4][2];
        #pragma unroll
        for (int ks = 0; ks < 4; ++ks) {
            const int co = (kt * 8 + ks * 2) * 32;
            #pragma unroll
            for (int mt = 0; mt < 4; ++mt) af[ks][mt] = Ab[aIdx[mt] + co];
            #pragma unroll
            for (int nt = 0; nt < 2; ++nt) bf[ks][nt] = Bb[bIdx[nt] + co];
        }
        #pragma unroll
        for (int ks = 0; ks < 4; ++ks)
            #pragma unroll
            for (int mt = 0; mt < 4; ++mt)
                #pragma unroll
                for (int nt = 0; nt < 2; ++nt)
                    acc[mt][nt] = __builtin_amdgcn_mfma_i32_32x32x32_i8(
                        af[ks][mt], bf[ks][nt], acc[mt][nt], 0, 0, 0);
    }

    // C/D (32x32): col = lane&31 (=fr), row = (reg&3) + 8*(reg>>2) + 4*h
    // ---- col partials (cheap direction) ----
    #pragma unroll
    for (int nt = 0; nt < 2; ++nt) {
        v16i c = vmax16(vmax16(acc[0][nt], acc[1][nt]),
                        vmax16(acc[2][nt], acc[3][nt]));
        int v = c[0];
        #pragma unroll
        for (int i = 1; i < 16; ++i) v = imax(v, c[i]);
        v = imax(v, __shfl_xor(v, 32, 64));
        if (h == 0) {
            int col = col0 + wn * 64 + nt * 32 + fr;
            Pcol[(size_t)col * NPCOL + by * 2 + wm] = v;   // sole writer
        }
    }

    // ---- row partials via LDS transpose (wave-private scratch, no barriers) ----
    int* T = (int*)(void*)S + wave * 1152;   // 32 x 36 ints per wave
    const int rrow = lane & 31, seg = lane >> 5;
    #pragma unroll
    for (int mt = 0; mt < 4; ++mt) {
        v16i m = vmax16(acc[mt][0], acc[mt][1]);
        #pragma unroll
        for (int reg = 0; reg < 16; ++reg) {
            int rl = (reg & 3) + 8 * (reg >> 2) + 4 * h;   // local row 0..31
            T[rl * 36 + fr] = m[reg];
        }
        __builtin_amdgcn_s_waitcnt(0);                     // lgkm drain before read-back
        const v4i* tr = (const v4i*)(T + rrow * 36 + seg * 16);
        v4i a0 = tr[0], a1 = tr[1], a2 = tr[2], a3 = tr[3];
        v4i m01 = { imax(a0[0],a1[0]), imax(a0[1],a1[1]), imax(a0[2],a1[2]), imax(a0[3],a1[3]) };
        v4i m23 = { imax(a2[0],a3[0]), imax(a2[1],a3[1]), imax(a2[2],a3[2]), imax(a2[3],a3[3]) };
        int v = imax(imax(m01[0], m23[0]), imax(m01[1], m23[1]));
        v = imax(v, imax(imax(m01[2], m23[2]), imax(m01[3], m23[3])));
        v = imax(v, __shfl_xor(v, 32, 64));                // combine the two 16-col segments
        if (seg == 0) {
            int row = row0 + wm * 128 + mt * 32 + rrow;
            Prow[(size_t)row * NPROW + bx * 2 + wn] = v;   // sole writer
        }
        __builtin_amdgcn_s_waitcnt(0);                     // reads done before next mt reuses T
    }
}

// ---- 3: fused reduce + entropy + last-block writes out ----
// 256 blocks; block handles 32 row-targets and 32 col-targets. Partial
// entropy sums -> device atomicAdd into accum; 256th block writes out.
__global__ __launch_bounds__(256) void reduce_fin_kernel(
        const int* __restrict__ Prow, const int* __restrict__ Pcol,
        float* __restrict__ accum, int* __restrict__ done,
        float* __restrict__ out) {
    const int blk  = blockIdx.x;
    const int lane = threadIdx.x & 63;
    const int wave = threadIdx.x >> 6;
    const float dq = 1.0f / (QSCALE * QSCALE);

    float sr = 0.0f, sc = 0.0f;
    for (int i = wave; i < 32; i += 4) {
        int t = blk * 32 + i;
        const int* p = Prow + (size_t)t * NPROW;
        int v = imax(p[lane], p[lane + 64]);
        #pragma unroll
        for (int off = 1; off < 64; off <<= 1) v = imax(v, __shfl_xor(v, off, 64));
        int vc = Pcol[(size_t)t * NPCOL + lane];
        #pragma unroll
        for (int off = 1; off < 64; off <<= 1) vc = imax(vc, __shfl_xor(vc, off, 64));
        if (lane == 0) {
            float f = (float)v * dq;
            float z = f * (1.0f / 0.3f);
            float c = -0.5f * z * z + 0.28503427f;
            sr += expf(c) * c;
            f = (float)vc * dq;
            z = f * (1.0f / 0.3f);
            c = -0.5f * z * z + 0.28503427f;
            sc += expf(c) * c;
        }
    }
    __shared__ float R[8];
    if (lane == 0) { R[wave * 2] = sr; R[wave * 2 + 1] = sc; }
    __syncthreads();
    if (threadIdx.x == 0) {
        atomicAdd(&accum[0], R[0] + R[2] + R[4] + R[6]);
        atomicAdd(&accum[1], R[1] + R[3] + R[5] + R[7]);
        __threadfence();
        int r = atomicAdd(done, 1);
        if (r == 255) {   // last block: all 256 adds visible
            float a0 = __hip_atomic_load(&accum[0], __ATOMIC_ACQUIRE, __HIP_MEMORY_SCOPE_AGENT);
            float a1 = __hip_atomic_load(&accum[1], __ATOMIC_ACQUIRE, __HIP_MEMORY_SCOPE_AGENT);
            out[0] = -a0;
            out[1] = -a1;
        }
    }
}

extern "C" void kernel_launch(void* const* d_in, const int* in_sizes, int n_in,
                              void* d_out, int out_size, void* d_ws, size_t ws_size,
                              hipStream_t stream) {
    const float* ex = (const float*)d_in[0];
    const float* ey = (const float*)d_in[1];
    float* out = (float*)d_out;

    char* ws   = (char*)d_ws;
    char* Xqf  = ws;                                             // 6.29 MB fragment-major
    char* Yqf  = ws + (size_t)NROWS * DDIM;                      // 6.29 MB fragment-major
    int*  Prow = (int*)(ws + (size_t)2 * NROWS * DDIM);          // 8192*128*4 = 4 MB
    int*  Pcol = Prow + (size_t)NROWS * NPROW;                   // 8192*64*4  = 2 MB
    float* accum = (float*)(Pcol + (size_t)NROWS * NPCOL);       // 2 floats
    int*  done   = (int*)(accum + 2);                            // 1 int

    hipLaunchKernelGGL(norm_quant_kernel, dim3(2 * NROWS / 4), dim3(256), 0, stream,
                       ex, ey, Xqf, Yqf, accum, done);
    hipLaunchKernelGGL(gemm_max_kernel, dim3(2048), dim3(256), 0, stream,
                       Xqf, Yqf, Prow, Pcol);
    hipLaunchKernelGGL(reduce_fin_kernel, dim3(256), dim3(256), 0, stream,
                       Prow, Pcol, accum, done, out);
}